// Round 9
// baseline (152.532 us; speedup 1.0000x reference)
//
#include <hip/hip_runtime.h>

typedef int v4i __attribute__((ext_vector_type(4)));
typedef unsigned int u32;
typedef __attribute__((address_space(1))) const u32 gas_u32;
typedef __attribute__((address_space(3))) u32 las_u32;

#define THREADS 1024
#define NWAVES 16
#define EPT 8                            // edges per thread per chunk
#define CHUNK (THREADS * EPT)            // 8192
#define NBLK 256                         // persistent: 1 block per CU
#define PART_BITS 18
#define PART_NODES (1 << PART_BITS)      // 262144 nodes per partition
#define PART_WORDS (PART_NODES / 16)     // 16384 words = 64 KB
#define NPART 4
#define TBL 450                          // NUM_RELS * 9
#define FILL_WAVE_WORDS (PART_WORDS / NWAVES)  // 1024 words per wave
#define FILL_PER_WAVE (FILL_WAVE_WORDS / 256)  // 4 DMA instrs per wave
#define ZPAD_BYTE (2u * PART_WORDS * 4u)       // byte 131072: zeroed pad word

// Barrier WITHOUT vmcnt drain (DMA/stream loads stay in flight); rule-18 fence.
#define BAR() do {                                            \
    asm volatile("s_waitcnt lgkmcnt(0)" ::: "memory");        \
    __builtin_amdgcn_s_barrier();                             \
    __builtin_amdgcn_sched_barrier(0);                        \
} while (0)

// Counted vmcnt wait (T4): keep the N newest loads in flight.
#define WAITVM(n) do {                                        \
    asm volatile("s_waitcnt vmcnt(" #n ")" ::: "memory");     \
    __builtin_amdgcn_sched_barrier(0);                        \
} while (0)

__global__ void zero_kernel(float* __restrict__ out, int n) {
    int i = blockIdx.x * blockDim.x + threadIdx.x;
    if (i < n) out[i] = 0.0f;
}

// Pack node_type (0..2) into 2 bits/node: 16 nodes per uint32 (256 KB total).
__global__ void pack_nt_kernel(const int* __restrict__ nt,
                               unsigned int* __restrict__ packed,
                               int nwords, int N) {
    int i = blockIdx.x * blockDim.x + threadIdx.x;
    if (i >= nwords) return;
    unsigned int word = 0;
    int base = i * 16;
    if (base + 16 <= N) {
        #pragma unroll
        for (int j = 0; j < 4; ++j) {
            int4 v = *reinterpret_cast<const int4*>(nt + base + j * 4);
            word |= (unsigned)(v.x & 3) << (2 * (j * 4 + 0));
            word |= (unsigned)(v.y & 3) << (2 * (j * 4 + 1));
            word |= (unsigned)(v.z & 3) << (2 * (j * 4 + 2));
            word |= (unsigned)(v.w & 3) << (2 * (j * 4 + 3));
        }
    } else {
        for (int j = 0; base + j < N; ++j)
            word |= (unsigned)(nt[base + j] & 3) << (2 * j);
    }
    packed[i] = word;
}

// DMA one 64 KB partition p into LDS half (p&1). Wave-uniform LDS base +
// lane x 16B (m104 pattern); per-lane global source. Zero VGPR cost.
__device__ __forceinline__ void dma_fill(const u32* __restrict__ pnt,
                                         u32* lds0, int p, int wv, int lane) {
    const u32* g = pnt + (size_t)p * PART_WORDS + wv * FILL_WAVE_WORDS + lane * 4;
    u32* l = lds0 + (p & 1) * PART_WORDS + wv * FILL_WAVE_WORDS;
    #pragma unroll
    for (int i = 0; i < FILL_PER_WAVE; ++i)
        __builtin_amdgcn_global_load_lds((gas_u32*)(g + i * 256),
                                         (las_u32*)(l + i * 256), 16, 0, 0);
}

// Gather pass for partition P. afx = masked byte addr | partition id (2 LSBs).
// In-partition lanes read their word (lands in the resident half by
// construction); others read the zeroed pad word (uniform addr = broadcast).
// bfe of 0 contributes 0, so accumulation is unconditional.
template <int P>
__device__ __forceinline__ void gather_phase(const u32* lds0,
                                             const u32 (&axs)[EPT], const u32 (&axd)[EPT],
                                             const u32 (&shs)[EPT], const u32 (&shd)[EPT],
                                             int (&enc)[EPT]) {
    #pragma unroll
    for (int k = 0; k < EPT; ++k) {
        u32 as = axs[k];
        u32 aaddr = ((as & 3u) == (u32)P) ? (as - (u32)P) : ZPAD_BYTE;
        u32 rs = *reinterpret_cast<const u32*>(
                     reinterpret_cast<const char*>(lds0) + aaddr);
        u32 ad = axd[k];
        u32 daddr = ((ad & 3u) == (u32)P) ? (ad - (u32)P) : ZPAD_BYTE;
        u32 rd = *reinterpret_cast<const u32*>(
                     reinterpret_cast<const char*>(lds0) + daddr);
        enc[k] += (int)((rs >> shs[k]) & 3u) * 3;
        enc[k] += (int)((rd >> shd[k]) & 3u);
    }
}

__launch_bounds__(THREADS)
__global__ void edge_score_k(const u32* __restrict__ pnt,
                             const int* __restrict__ et_g,
                             const int* __restrict__ es_g,
                             const int* __restrict__ ed_g,
                             const int* __restrict__ eb_g,
                             const float* __restrict__ wt,
                             float* __restrict__ out,
                             int nchunk) {
    // [0,32768): two 64 KB partition buffers | [32768,32784): zero pad |
    // [32784,...): 450-entry weight table.
    __shared__ __align__(16) u32 lds_all[2 * PART_WORDS + 16 + TBL];
    u32* lds0 = lds_all;
    float* lw = reinterpret_cast<float*>(lds_all + 2 * PART_WORDS + 16);

    const int tid  = threadIdx.x;
    const int lane = tid & 63;
    const int wv   = tid >> 6;

    if (tid < 16) lds_all[2 * PART_WORDS + tid] = 0u;   // zero pad words
    for (int i = tid; i < TBL; i += THREADS) lw[i] = wt[i];

    dma_fill(pnt, lds0, 0, wv, lane);    // prologue: partition 0 -> buf half 0

    const long blk0 = (long)blockIdx.x * ((long)nchunk * CHUNK);
    const long lb   = (long)wv * (64 * EPT) + (long)lane * 4;

    for (int c = 0; c < nchunk; ++c) {
        const long cb = blk0 + (long)c * CHUNK + lb;

        // ---------------- phase 0 ----------------
        BAR();   // BARa: prev chunk's gather(3)+epilogue done (buf1 free); lds inits visible
        v4i et0 = __builtin_nontemporal_load((const v4i*)(et_g + cb));
        v4i et1 = __builtin_nontemporal_load((const v4i*)(et_g + cb + 256));
        v4i sv0 = __builtin_nontemporal_load((const v4i*)(es_g + cb));
        v4i sv1 = __builtin_nontemporal_load((const v4i*)(es_g + cb + 256));
        v4i dv0 = __builtin_nontemporal_load((const v4i*)(ed_g + cb));
        v4i dv1 = __builtin_nontemporal_load((const v4i*)(ed_g + cb + 256));
        __builtin_amdgcn_sched_barrier(0);   // streams issue before fill DMA
        dma_fill(pnt, lds0, 1, wv, lane);    // partition 1 -> buf half 1

        int enc[EPT]; u32 axs[EPT], axd[EPT], shs[EPT], shd[EPT];
        #pragma unroll
        for (int q = 0; q < 4; ++q) {
            // compiler waits streams here (vmcnt<=4) => own p0 DMA also done
            enc[q]     = et0[q] * 9;
            enc[4 + q] = et1[q] * 9;
            u32 s0 = (u32)sv0[q], s1 = (u32)sv1[q];
            u32 d0 = (u32)dv0[q], d1 = (u32)dv1[q];
            axs[q]     = (((s0 >> 4) << 2) & 0x1FFFFu) | (s0 >> PART_BITS);
            axs[4 + q] = (((s1 >> 4) << 2) & 0x1FFFFu) | (s1 >> PART_BITS);
            axd[q]     = (((d0 >> 4) << 2) & 0x1FFFFu) | (d0 >> PART_BITS);
            axd[4 + q] = (((d1 >> 4) << 2) & 0x1FFFFu) | (d1 >> PART_BITS);
            shs[q]     = (s0 & 15u) << 1;
            shs[4 + q] = (s1 & 15u) << 1;
            shd[q]     = (d0 & 15u) << 1;
            shd[4 + q] = (d1 & 15u) << 1;
        }
        BAR();   // BARb: every wave certified its p0 fill complete
        gather_phase<0>(lds0, axs, axd, shs, shd, enc);

        // ---------------- phase 1 ----------------
        BAR();                               // BARa: gather(0) done (buf0 free)
        dma_fill(pnt, lds0, 2, wv, lane);    // partition 2 -> buf half 0
        WAITVM(4);                           // own p1 fill landed; p2 in flight
        BAR();                               // BARb
        gather_phase<1>(lds0, axs, axd, shs, shd, enc);

        // ---------------- phase 2 ----------------
        BAR();                               // BARa: gather(1) done (buf1 free)
        dma_fill(pnt, lds0, 3, wv, lane);    // partition 3 -> buf half 1
        WAITVM(4);                           // own p2 fill landed; p3 in flight
        BAR();                               // BARb
        gather_phase<2>(lds0, axs, axd, shs, shd, enc);

        // ---------------- phase 3 ----------------
        BAR();                               // BARa: gather(2) done (buf0 free)
        dma_fill(pnt, lds0, 0, wv, lane);    // partition 0 for NEXT chunk
        v4i eb0 = __builtin_nontemporal_load((const v4i*)(eb_g + cb));
        v4i eb1 = __builtin_nontemporal_load((const v4i*)(eb_g + cb + 256));
        WAITVM(6);                           // own p3 fill landed; p0next+eb in flight
        BAR();                               // BARb
        gather_phase<3>(lds0, axs, axd, shs, shd, enc);

        // ---------------- epilogue ----------------
        float val[EPT];
        #pragma unroll
        for (int k = 0; k < EPT; ++k) val[k] = lw[enc[k]];

        int wb0 = __shfl(eb0[0], 0);         // first edge of wave window
        int wbL = __shfl(eb1[3], 63);        // last edge of wave window
        if (wb0 == wbL) {                    // sorted => whole window one graph
            float ssum = 0.0f;
            #pragma unroll
            for (int k = 0; k < EPT; ++k) ssum += val[k];
            #pragma unroll
            for (int off = 32; off >= 1; off >>= 1)
                ssum += __shfl_down(ssum, off);
            if (lane == 0) atomicAdd(&out[wb0], ssum);
        } else {
            float acc = 0.0f; int cur = -1;
            #pragma unroll
            for (int k = 0; k < EPT; ++k) {
                int bb = (k < 4) ? eb0[k] : eb1[k - 4];    // static index
                if (bb != cur) {
                    if (cur >= 0) atomicAdd(&out[cur], acc);
                    cur = bb; acc = 0.0f;
                }
                acc += val[k];
            }
            if (cur >= 0) atomicAdd(&out[cur], acc);
        }
    }
}

// Per-edge fallback / tail kernel (direct gathers; correctness path).
__global__ void edge_score_simple(const int* __restrict__ nt,
                                  const int* __restrict__ et,
                                  const int* __restrict__ es,
                                  const int* __restrict__ ed,
                                  const int* __restrict__ eb,
                                  const float* __restrict__ w,
                                  float* __restrict__ out,
                                  long e0, long E) {
    long e = e0 + (long)blockIdx.x * blockDim.x + threadIdx.x;
    if (e >= E) return;
    int enc = et[e] * 9 + nt[es[e]] * 3 + nt[ed[e]];
    atomicAdd(&out[eb[e]], w[enc]);
}

extern "C" void kernel_launch(void* const* d_in, const int* in_sizes, int n_in,
                              void* d_out, int out_size, void* d_ws, size_t ws_size,
                              hipStream_t stream) {
    const int*   node_type  = (const int*)d_in[0];
    const int*   edge_type  = (const int*)d_in[1];
    const int*   edge_index = (const int*)d_in[2];   // [2, E]: src then dst
    const int*   edge_batch = (const int*)d_in[3];
    const float* w          = (const float*)d_in[4];
    float* out = (float*)d_out;

    long N = in_sizes[0];
    long E = in_sizes[1];
    const int* esrc = edge_index;
    const int* edst = edge_index + E;

    // d_out is poisoned once and never re-poisoned between replays; we
    // accumulate with atomics, so zero it at the start of every launch.
    zero_kernel<<<(out_size + 255) / 256, 256, 0, stream>>>(out, out_size);

    int  nwords = (int)((N + 15) / 16);
    long nchunk = E / ((long)NBLK * CHUNK);            // 8 for E = 2^24
    bool fast_ok = (ws_size >= (size_t)nwords * 4) &&
                   (N <= (long)NPART * PART_NODES) && (nchunk > 0);

    if (fast_ok) {
        unsigned int* pnt = (unsigned int*)d_ws;
        pack_nt_kernel<<<(nwords + 255) / 256, 256, 0, stream>>>(node_type, pnt, nwords, (int)N);

        edge_score_k<<<NBLK, THREADS, 0, stream>>>(
            pnt, edge_type, esrc, edst, edge_batch, w, out, (int)nchunk);

        long covered = (long)NBLK * nchunk * CHUNK;
        long rem     = E - covered;                    // 0 for this dataset
        if (rem > 0) {
            int tb = (int)((rem + 255) / 256);
            edge_score_simple<<<tb, 256, 0, stream>>>(
                node_type, edge_type, esrc, edst, edge_batch, w, out, covered, E);
        }
    } else {
        int tb = (int)((E + 255) / 256);
        edge_score_simple<<<tb, 256, 0, stream>>>(
            node_type, edge_type, esrc, edst, edge_batch, w, out, 0, E);
    }
}

// Round 10
// 151.768 us; speedup vs baseline: 1.0050x; 1.0050x over previous
//
#include <hip/hip_runtime.h>

typedef int v4i __attribute__((ext_vector_type(4)));
typedef unsigned int u32;
typedef __attribute__((address_space(1))) const u32 gas_u32;
typedef __attribute__((address_space(3))) u32 las_u32;

#define THREADS 1024
#define NWAVES 16
#define EPT 8                            // edges per thread per chunk
#define CHUNK (THREADS * EPT)            // 8192
#define NBLK 256                         // persistent: 1 block per CU
#define PART_BITS 18
#define PART_NODES (1 << PART_BITS)      // 262144 nodes per partition
#define PART_WORDS (PART_NODES / 16)     // 16384 words = 64 KB
#define NPART 4
#define TBL 450                          // NUM_RELS * 9
#define FILL_WAVE_WORDS (PART_WORDS / NWAVES)  // 1024 words per wave
#define FILL_PER_WAVE (FILL_WAVE_WORDS / 256)  // 4 DMA instrs per wave
#define PAD_WIDX (2u * PART_WORDS)             // zeroed pad word index

// Barrier WITHOUT vmcnt drain (DMA/stream loads stay in flight); rule-18 fence.
#define BAR() do {                                            \
    asm volatile("s_waitcnt lgkmcnt(0)" ::: "memory");        \
    __builtin_amdgcn_s_barrier();                             \
    __builtin_amdgcn_sched_barrier(0);                        \
} while (0)

// Counted vmcnt wait (T4): keep the N newest loads in flight.
#define WAITVM(n) do {                                        \
    asm volatile("s_waitcnt vmcnt(" #n ")" ::: "memory");     \
    __builtin_amdgcn_sched_barrier(0);                        \
} while (0)

__global__ void zero_kernel(float* __restrict__ out, int n) {
    int i = blockIdx.x * blockDim.x + threadIdx.x;
    if (i < n) out[i] = 0.0f;
}

// Pack node_type (0..2) into 2 bits/node: 16 nodes per uint32 (256 KB total).
__global__ void pack_nt_kernel(const int* __restrict__ nt,
                               unsigned int* __restrict__ packed,
                               int nwords, int N) {
    int i = blockIdx.x * blockDim.x + threadIdx.x;
    if (i >= nwords) return;
    unsigned int word = 0;
    int base = i * 16;
    if (base + 16 <= N) {
        #pragma unroll
        for (int j = 0; j < 4; ++j) {
            int4 v = *reinterpret_cast<const int4*>(nt + base + j * 4);
            word |= (unsigned)(v.x & 3) << (2 * (j * 4 + 0));
            word |= (unsigned)(v.y & 3) << (2 * (j * 4 + 1));
            word |= (unsigned)(v.z & 3) << (2 * (j * 4 + 2));
            word |= (unsigned)(v.w & 3) << (2 * (j * 4 + 3));
        }
    } else {
        for (int j = 0; base + j < N; ++j)
            word |= (unsigned)(nt[base + j] & 3) << (2 * j);
    }
    packed[i] = word;
}

// DMA one 64 KB partition p into LDS half (p&1). Wave-uniform LDS base +
// lane x 16B (m104 pattern); per-lane global source. Zero VGPR cost.
__device__ __forceinline__ void dma_fill(const u32* __restrict__ pnt,
                                         u32* lds0, int p, int wv, int lane) {
    const u32* g = pnt + (size_t)p * PART_WORDS + wv * FILL_WAVE_WORDS + lane * 4;
    u32* l = lds0 + (p & 1) * PART_WORDS + wv * FILL_WAVE_WORDS;
    #pragma unroll
    for (int i = 0; i < FILL_PER_WAVE; ++i)
        __builtin_amdgcn_global_load_lds((gas_u32*)(g + i * 256),
                                         (las_u32*)(l + i * 256), 16, 0, 0);
}

// Gather pass for compile-time partition P; addresses computed INLINE (no
// persistent arrays -> no spill). Out-of-partition lanes read the zeroed pad
// word (uniform addr = broadcast); bfe of 0 contributes 0 -> unconditional add.
template <int P>
__device__ __forceinline__ void gather_phase(const u32* lds_all,
                                             const int (&sv)[EPT], const int (&dv)[EPT],
                                             int (&enc)[EPT]) {
    #pragma unroll
    for (int k = 0; k < EPT; ++k) {
        u32 s = (u32)sv[k];
        u32 widx_s = ((s & (u32)(PART_NODES - 1)) >> 4) + ((P & 1) ? PART_WORDS : 0);
        u32 idx_s  = ((s >> PART_BITS) == (u32)P) ? widx_s : PAD_WIDX;
        u32 word_s = lds_all[idx_s];
        u32 d = (u32)dv[k];
        u32 widx_d = ((d & (u32)(PART_NODES - 1)) >> 4) + ((P & 1) ? PART_WORDS : 0);
        u32 idx_d  = ((d >> PART_BITS) == (u32)P) ? widx_d : PAD_WIDX;
        u32 word_d = lds_all[idx_d];
        enc[k] += (int)((word_s >> ((s & 15u) << 1)) & 3u) * 3;
        enc[k] += (int)((word_d >> ((d & 15u) << 1)) & 3u);
    }
}

__launch_bounds__(THREADS)
__global__ void edge_score_k(const u32* __restrict__ pnt,
                             const int* __restrict__ et_g,
                             const int* __restrict__ es_g,
                             const int* __restrict__ ed_g,
                             const int* __restrict__ eb_g,
                             const float* __restrict__ wt,
                             float* __restrict__ out,
                             int nchunk) {
    // [0,16384): half0 | [16384,32768): half1 | [32768,32784): zero pad |
    // then the 450-entry weight table.
    __shared__ __align__(16) u32 lds_all[2 * PART_WORDS + 16 + TBL];
    float* lw = reinterpret_cast<float*>(lds_all + 2 * PART_WORDS + 16);

    const int tid  = threadIdx.x;
    const int lane = tid & 63;
    const int wv   = tid >> 6;

    if (tid < 16) lds_all[2 * PART_WORDS + tid] = 0u;   // zero pad words
    for (int i = tid; i < TBL; i += THREADS) lw[i] = wt[i];

    dma_fill(pnt, lds_all, 0, wv, lane);   // prologue: partition 0 -> half 0

    const long blk0 = (long)blockIdx.x * ((long)nchunk * CHUNK);
    const long lb   = (long)wv * (64 * EPT) + (long)lane * 4;

    for (int c = 0; c < nchunk; ++c) {
        const long cb = blk0 + (long)c * CHUNK + lb;

        // -------- phase 0 (gather partition 0, half0) --------
        // BARa0: prev chunk's gather(3)+epilogue done (half1 free for p1 fill);
        // prev epilogue's eb-consume drained each wave's p0 fill -> p0 resident.
        BAR();
        v4i et0 = __builtin_nontemporal_load((const v4i*)(et_g + cb));
        v4i et1 = __builtin_nontemporal_load((const v4i*)(et_g + cb + 256));
        v4i sv0 = __builtin_nontemporal_load((const v4i*)(es_g + cb));
        v4i sv1 = __builtin_nontemporal_load((const v4i*)(es_g + cb + 256));
        v4i dv0 = __builtin_nontemporal_load((const v4i*)(ed_g + cb));
        v4i dv1 = __builtin_nontemporal_load((const v4i*)(ed_g + cb + 256));
        __builtin_amdgcn_sched_barrier(0);   // streams issue before fill DMA
        dma_fill(pnt, lds_all, 1, wv, lane); // partition 1 -> half 1

        int enc[EPT], sv[EPT], dv[EPT];
        #pragma unroll
        for (int q = 0; q < 4; ++q) {
            // auto vmcnt(4) here: streams retired, p1 fill stays in flight
            enc[q]     = et0[q] * 9;
            enc[4 + q] = et1[q] * 9;
            sv[q]      = sv0[q];
            sv[4 + q]  = sv1[q];
            dv[q]      = dv0[q];
            dv[4 + q]  = dv1[q];
        }
        gather_phase<0>(lds_all, sv, dv, enc);

        // -------- phase 1 (gather partition 1, half1) --------
        BAR();                                // BARa1: gather(0) done, half0 free
        dma_fill(pnt, lds_all, 2, wv, lane);  // partition 2 -> half 0
        WAITVM(4);                            // own p1 fill landed (p2 in flight)
        BAR();                                // BARb1: p1 resident blockwide
        gather_phase<1>(lds_all, sv, dv, enc);

        // -------- phase 2 (gather partition 2, half0) --------
        BAR();                                // BARa2: gather(1) done, half1 free
        dma_fill(pnt, lds_all, 3, wv, lane);  // partition 3 -> half 1
        WAITVM(4);                            // own p2 fill landed (p3 in flight)
        BAR();                                // BARb2
        gather_phase<2>(lds_all, sv, dv, enc);

        // -------- phase 3 (gather partition 3, half1) --------
        BAR();                                // BARa3: gather(2) done, half0 free
        dma_fill(pnt, lds_all, 0, wv, lane);  // partition 0 for NEXT chunk
        v4i eb0 = __builtin_nontemporal_load((const v4i*)(eb_g + cb));
        v4i eb1 = __builtin_nontemporal_load((const v4i*)(eb_g + cb + 256));
        WAITVM(6);                            // own p3 fill landed (p0next+eb in flight)
        BAR();                                // BARb3
        gather_phase<3>(lds_all, sv, dv, enc);

        // -------- epilogue --------
        float val[EPT];
        #pragma unroll
        for (int k = 0; k < EPT; ++k) val[k] = lw[enc[k]];

        int wb0 = __shfl(eb0[0], 0);          // first edge of wave window
        int wbL = __shfl(eb1[3], 63);         // last edge of wave window
        if (wb0 == wbL) {                     // sorted => whole window one graph
            float ssum = 0.0f;
            #pragma unroll
            for (int k = 0; k < EPT; ++k) ssum += val[k];
            #pragma unroll
            for (int off = 32; off >= 1; off >>= 1)
                ssum += __shfl_down(ssum, off);
            if (lane == 0) atomicAdd(&out[wb0], ssum);
        } else {
            float acc = 0.0f; int cur = -1;
            #pragma unroll
            for (int k = 0; k < EPT; ++k) {
                int bb = (k < 4) ? eb0[k] : eb1[k - 4];    // static index
                if (bb != cur) {
                    if (cur >= 0) atomicAdd(&out[cur], acc);
                    cur = bb; acc = 0.0f;
                }
                acc += val[k];
            }
            if (cur >= 0) atomicAdd(&out[cur], acc);
        }
    }
}

// Per-edge fallback / tail kernel (direct gathers; correctness path).
__global__ void edge_score_simple(const int* __restrict__ nt,
                                  const int* __restrict__ et,
                                  const int* __restrict__ es,
                                  const int* __restrict__ ed,
                                  const int* __restrict__ eb,
                                  const float* __restrict__ w,
                                  float* __restrict__ out,
                                  long e0, long E) {
    long e = e0 + (long)blockIdx.x * blockDim.x + threadIdx.x;
    if (e >= E) return;
    int enc = et[e] * 9 + nt[es[e]] * 3 + nt[ed[e]];
    atomicAdd(&out[eb[e]], w[enc]);
}

extern "C" void kernel_launch(void* const* d_in, const int* in_sizes, int n_in,
                              void* d_out, int out_size, void* d_ws, size_t ws_size,
                              hipStream_t stream) {
    const int*   node_type  = (const int*)d_in[0];
    const int*   edge_type  = (const int*)d_in[1];
    const int*   edge_index = (const int*)d_in[2];   // [2, E]: src then dst
    const int*   edge_batch = (const int*)d_in[3];
    const float* w          = (const float*)d_in[4];
    float* out = (float*)d_out;

    long N = in_sizes[0];
    long E = in_sizes[1];
    const int* esrc = edge_index;
    const int* edst = edge_index + E;

    // d_out is poisoned once and never re-poisoned between replays; we
    // accumulate with atomics, so zero it at the start of every launch.
    zero_kernel<<<(out_size + 255) / 256, 256, 0, stream>>>(out, out_size);

    int  nwords = (int)((N + 15) / 16);
    long nchunk = E / ((long)NBLK * CHUNK);            // 8 for E = 2^24
    bool fast_ok = (ws_size >= (size_t)nwords * 4) &&
                   (N <= (long)NPART * PART_NODES) && (nchunk > 0);

    if (fast_ok) {
        unsigned int* pnt = (unsigned int*)d_ws;
        pack_nt_kernel<<<(nwords + 255) / 256, 256, 0, stream>>>(node_type, pnt, nwords, (int)N);

        edge_score_k<<<NBLK, THREADS, 0, stream>>>(
            pnt, edge_type, esrc, edst, edge_batch, w, out, (int)nchunk);

        long covered = (long)NBLK * nchunk * CHUNK;
        long rem     = E - covered;                    // 0 for this dataset
        if (rem > 0) {
            int tb = (int)((rem + 255) / 256);
            edge_score_simple<<<tb, 256, 0, stream>>>(
                node_type, edge_type, esrc, edst, edge_batch, w, out, covered, E);
        }
    } else {
        int tb = (int)((E + 255) / 256);
        edge_score_simple<<<tb, 256, 0, stream>>>(
            node_type, edge_type, esrc, edst, edge_batch, w, out, 0, E);
    }
}